// Round 1
// baseline (286.642 us; speedup 1.0000x reference)
//
#include <hip/hip_runtime.h>
#include <cstdint>

typedef unsigned short u16;
typedef u16   u16x4  __attribute__((ext_vector_type(4)));
typedef u16   u16x8  __attribute__((ext_vector_type(8)));
typedef __bf16 bf16x8 __attribute__((ext_vector_type(8)));
typedef float f32x4  __attribute__((ext_vector_type(4)));

__device__ __forceinline__ u16 f2bf(float f) {
    uint32_t u = __builtin_bit_cast(uint32_t, f);
    u += 0x7fffu + ((u >> 16) & 1u);   // round-to-nearest-even
    return (u16)(u >> 16);
}
__device__ __forceinline__ float bf2f(u16 v) {
    uint32_t u = ((uint32_t)v) << 16;
    return __builtin_bit_cast(float, u);
}
// async global->LDS, 16B per lane. LDS dest is wave-uniform base + lane*16.
__device__ __forceinline__ void gload_lds16(const u16* g, u16* l) {
    __builtin_amdgcn_global_load_lds((const __attribute__((address_space(1))) void*)g,
                                     (__attribute__((address_space(3))) void*)l,
                                     16, 0, 0);
}

// ---------------- cast X fp32 -> bf16 ----------------
__global__ __launch_bounds__(256) void cast_x_kernel(const float* __restrict__ X,
                                                     u16* __restrict__ Xb) {
    const int idx = blockIdx.x * 256 + threadIdx.x;   // 8192 blocks * 256 * 4 elems = 8388608
    typedef float f4 __attribute__((ext_vector_type(4)));
    f4 f = ((const f4*)X)[idx];
    u16x4 o;
    o[0] = f2bf(f[0]); o[1] = f2bf(f[1]); o[2] = f2bf(f[2]); o[3] = f2bf(f[3]);
    ((u16x4*)Xb)[idx] = o;
}

// ------------- transpose-cast W [K][N] fp32 -> Wt [N][K] bf16 -------------
__global__ __launch_bounds__(256) void cast_wt_kernel(const float* __restrict__ Wq,
                                                      const float* __restrict__ Wk,
                                                      const float* __restrict__ Wv,
                                                      u16* __restrict__ Wt) {
    __shared__ u16 tile[64][72];
    const float* W = (blockIdx.z == 0) ? Wq : (blockIdx.z == 1) ? Wk : Wv;
    u16* out = Wt + ((size_t)blockIdx.z << 20);
    const int nt = blockIdx.x * 64, kt = blockIdx.y * 64;
    const int t = threadIdx.x, r = t >> 2, cq = (t & 3) * 16;
    typedef float f4 __attribute__((ext_vector_type(4)));
    const float* src = W + (size_t)(kt + r) * 1024 + nt + cq;
#pragma unroll
    for (int q = 0; q < 4; q++) {
        f4 f = ((const f4*)src)[q];
        tile[r][cq + q * 4 + 0] = f2bf(f[0]);
        tile[r][cq + q * 4 + 1] = f2bf(f[1]);
        tile[r][cq + q * 4 + 2] = f2bf(f[2]);
        tile[r][cq + q * 4 + 3] = f2bf(f[3]);
    }
    __syncthreads();
    u16x8 o0, o1;
#pragma unroll
    for (int e = 0; e < 8; e++) { o0[e] = tile[cq + e][r]; o1[e] = tile[cq + 8 + e][r]; }
    u16* dst = out + (size_t)(nt + r) * 1024 + kt + cq;
    *(u16x8*)dst = o0;
    *(u16x8*)(dst + 8) = o1;
}

// ------------- transpose V [b][s][e] bf16 -> Vt [b][e][s] bf16 -------------
__global__ __launch_bounds__(256) void transpose_v_kernel(const u16* __restrict__ V,
                                                          u16* __restrict__ Vt) {
    __shared__ u16 tile[64][72];
    const u16* src = V + ((size_t)blockIdx.z << 21);
    u16* dst = Vt + ((size_t)blockIdx.z << 21);
    const int st = blockIdx.x * 64, et = blockIdx.y * 64;
    const int t = threadIdx.x, r = t >> 2, cq = (t & 3) * 16;
    const u16* p = src + (size_t)(st + r) * 1024 + et + cq;
    u16x8 u0 = *(const u16x8*)p;
    u16x8 u1 = *(const u16x8*)(p + 8);
#pragma unroll
    for (int e = 0; e < 8; e++) { tile[r][cq + e] = u0[e]; tile[r][cq + 8 + e] = u1[e]; }
    __syncthreads();
    u16x8 o0, o1;
#pragma unroll
    for (int e = 0; e < 8; e++) { o0[e] = tile[cq + e][r]; o1[e] = tile[cq + 8 + e][r]; }
    u16* q = dst + (size_t)(et + r) * 2048 + st + cq;
    *(u16x8*)q = o0;
    *(u16x8*)(q + 8) = o1;
}

// ------------- shared GEMM core: C[M,N] = A[M,K] * Bt[N,K]^T -------------
// 128x128 tile, BK=32, 256 threads = 4 waves (2x2), 4x4 16x16 MFMA tiles/wave.
template <bool F32OUT>
__device__ __forceinline__ void gemm_bt_core(const u16* __restrict__ A,
                                             const u16* __restrict__ Bt,
                                             void* __restrict__ outp,
                                             const int ldk, const int ldo,
                                             const int kmax, const int m0, const int n0) {
    __shared__ u16 As[4096];   // [128][32]
    __shared__ u16 Bs[4096];   // [128][32]
    const int tid = (int)threadIdx.x;
    const int wave = tid >> 6, lane = tid & 63;
    const int wm = wave >> 1, wn = wave & 1;

    f32x4 acc[4][4] = {};

    // staging: each wave covers 32 rows of A-tile and 32 rows of Bt-tile via 2 issues each
    const int sr = lane >> 2;            // row within 16-row issue group
    const int sc = (lane & 3) * 8;       // col chunk (8 bf16 = 16B)
    const u16* gA = A  + (size_t)(m0 + wave * 32 + sr) * ldk + sc;
    const u16* gB = Bt + (size_t)(n0 + wave * 32 + sr) * ldk + sc;
    u16* lA = As + wave * 1024;          // wave-uniform LDS base
    u16* lB = Bs + wave * 1024;
    const size_t rstep = (size_t)ldk * 16;

    const u16* pa = As + (wm * 64 + (lane & 15)) * 32 + (lane >> 4) * 8;
    const u16* pb = Bs + (wn * 64 + (lane & 15)) * 32 + (lane >> 4) * 8;

    for (int k0 = 0; k0 < kmax; k0 += 32) {
        gload_lds16(gA + k0,         lA);
        gload_lds16(gA + k0 + rstep, lA + 512);
        gload_lds16(gB + k0,         lB);
        gload_lds16(gB + k0 + rstep, lB + 512);
        __syncthreads();
        bf16x8 a[4], b[4];
#pragma unroll
        for (int i = 0; i < 4; i++) a[i] = *(const bf16x8*)(pa + i * 512);
#pragma unroll
        for (int j = 0; j < 4; j++) b[j] = *(const bf16x8*)(pb + j * 512);
#pragma unroll
        for (int i = 0; i < 4; i++)
#pragma unroll
            for (int j = 0; j < 4; j++)
                acc[i][j] = __builtin_amdgcn_mfma_f32_16x16x32_bf16(a[i], b[j], acc[i][j], 0, 0, 0);
        __syncthreads();
    }

    // epilogue: C/D layout col=lane&15, row=(lane>>4)*4+reg  [m89/m91-verified]
    const int row0 = m0 + wm * 64 + ((lane >> 4) << 2);
    const int col0 = n0 + wn * 64 + (lane & 15);
    if constexpr (F32OUT) {
        float* o = (float*)outp;
#pragma unroll
        for (int i = 0; i < 4; i++)
#pragma unroll
            for (int r = 0; r < 4; r++) {
                float* po = o + (size_t)(row0 + i * 16 + r) * ldo + col0;
#pragma unroll
                for (int j = 0; j < 4; j++) po[j * 16] = acc[i][j][r];
            }
    } else {
        u16* o = (u16*)outp;
#pragma unroll
        for (int i = 0; i < 4; i++)
#pragma unroll
            for (int r = 0; r < 4; r++) {
                u16* po = o + (size_t)(row0 + i * 16 + r) * ldo + col0;
#pragma unroll
                for (int j = 0; j < 4; j++) po[j * 16] = f2bf(acc[i][j][r]);
            }
    }
}

// QKV: X[8192,1024] * Wt[z][1024,1024]^T -> QKV[z][8192,1024] bf16
__global__ __launch_bounds__(256) void qkv_gemm_kernel(const u16* __restrict__ Xb,
                                                       const u16* __restrict__ Wt,
                                                       u16* __restrict__ QKV) {
    const int z = blockIdx.z;
    gemm_bt_core<false>(Xb, Wt + ((size_t)z << 20), QKV + ((size_t)z << 23),
                        1024, 1024, 1024, blockIdx.y * 128, blockIdx.x * 128);
}

// S = Q * K^T per batch, causal block skip (jt > it -> untouched)
__global__ __launch_bounds__(256) void s_gemm_kernel(const u16* __restrict__ QKV,
                                                     u16* __restrict__ S) {
    const int jt = blockIdx.x, it = blockIdx.y, b = blockIdx.z;
    if (jt > it) return;
    const u16* Q  = QKV + ((size_t)b << 21);
    const u16* Kp = QKV + ((size_t)1 << 23) + ((size_t)b << 21);
    gemm_bt_core<false>(Q, Kp, S + ((size_t)b << 22), 1024, 2048, 1024, it * 128, jt * 128);
}

// O = P * Vt^T per batch, k-loop truncated at the causal boundary
__global__ __launch_bounds__(256) void pv_gemm_kernel(const u16* __restrict__ P,
                                                      const u16* __restrict__ Vt,
                                                      float* __restrict__ O) {
    const int it = blockIdx.y, b = blockIdx.z;
    gemm_bt_core<true>(P + ((size_t)b << 22), Vt + ((size_t)b << 21), O + ((size_t)b << 21),
                       2048, 1024, (it + 1) * 128, it * 128, blockIdx.x * 128);
}

// --------- in-place causal softmax over S rows (scale 1/32), zeroes tail ---------
__global__ __launch_bounds__(256) void softmax_kernel(u16* __restrict__ S) {
    const int wave = threadIdx.x >> 6, lane = threadIdx.x & 63;
    const int g = blockIdx.x * 4 + wave;       // 0..8191
    const int b = g >> 11, i = g & 2047;
    u16* row = S + ((size_t)b << 22) + ((size_t)i << 11);
    const int n = i + 1;                        // valid keys
    const float NEG = -1e30f;
    float v[32];
    float m = NEG;
#pragma unroll
    for (int t = 0; t < 4; t++) {
        u16x8 u = *(const u16x8*)(row + t * 512 + lane * 8);
#pragma unroll
        for (int e = 0; e < 8; e++) {
            const int col = t * 512 + lane * 8 + e;
            float f = (col < n) ? bf2f(u[e]) : NEG;
            v[t * 8 + e] = f;
            m = fmaxf(m, f);
        }
    }
#pragma unroll
    for (int off = 32; off > 0; off >>= 1) m = fmaxf(m, __shfl_xor(m, off, 64));
    const float sc = 0.03125f * 1.44269504088896f;   // (1/sqrt(1024)) * log2(e)
    float s = 0.f;
#pragma unroll
    for (int t = 0; t < 32; t++) {
        const float e2 = (v[t] == NEG) ? 0.f : exp2f((v[t] - m) * sc);
        v[t] = e2;
        s += e2;
    }
#pragma unroll
    for (int off = 32; off > 0; off >>= 1) s += __shfl_xor(s, off, 64);
    const float inv = 1.f / s;
#pragma unroll
    for (int t = 0; t < 4; t++) {
        u16x8 o;
#pragma unroll
        for (int e = 0; e < 8; e++) o[e] = f2bf(v[t * 8 + e] * inv);
        *(u16x8*)(row + t * 512 + lane * 8) = o;
    }
}

extern "C" void kernel_launch(void* const* d_in, const int* in_sizes, int n_in,
                              void* d_out, int out_size, void* d_ws, size_t ws_size,
                              hipStream_t stream) {
    const float* X  = (const float*)d_in[0];
    const float* Wq = (const float*)d_in[1];
    const float* Wk = (const float*)d_in[2];
    const float* Wv = (const float*)d_in[3];
    float* out = (float*)d_out;

    // ws layout (u16 elems): Xb 8M | Wt 3M | QKV 24M | S 16M  -> ~107 MB
    u16* ws  = (u16*)d_ws;
    u16* Xb  = ws;                                   // 1<<23 elems (reused as Vt)
    u16* Wt  = Xb + ((size_t)1 << 23);               // 3 * (1<<20)
    u16* QKV = Wt + 3 * ((size_t)1 << 20);           // 3 * (1<<23)
    u16* S   = QKV + 3 * ((size_t)1 << 23);          // 1<<24
    u16* Vt  = Xb;                                   // Xb dead after QKV GEMM

    cast_x_kernel<<<8192, 256, 0, stream>>>(X, Xb);
    cast_wt_kernel<<<dim3(16, 16, 3), 256, 0, stream>>>(Wq, Wk, Wv, Wt);
    qkv_gemm_kernel<<<dim3(8, 64, 3), 256, 0, stream>>>(Xb, Wt, QKV);
    transpose_v_kernel<<<dim3(32, 16, 4), 256, 0, stream>>>(QKV + 2 * ((size_t)1 << 23), Vt);
    s_gemm_kernel<<<dim3(16, 16, 4), 256, 0, stream>>>(QKV, S);
    softmax_kernel<<<2048, 256, 0, stream>>>(S);
    pv_gemm_kernel<<<dim3(8, 16, 4), 256, 0, stream>>>(S, Vt, out);
}

// Round 2
// 282.573 us; speedup vs baseline: 1.0144x; 1.0144x over previous
//
#include <hip/hip_runtime.h>
#include <cstdint>
#include <cmath>

typedef unsigned short u16;
typedef u16   u16x4  __attribute__((ext_vector_type(4)));
typedef u16   u16x8  __attribute__((ext_vector_type(8)));
typedef __bf16 bf16x8 __attribute__((ext_vector_type(8)));
typedef float f32x4  __attribute__((ext_vector_type(4)));
typedef float f32x4n __attribute__((ext_vector_type(4)));

__device__ __forceinline__ u16 f2bf(float f) {
    uint32_t u = __builtin_bit_cast(uint32_t, f);
    u += 0x7fffu + ((u >> 16) & 1u);   // round-to-nearest-even
    return (u16)(u >> 16);
}
__device__ __forceinline__ float bf2f(u16 v) {
    uint32_t u = ((uint32_t)v) << 16;
    return __builtin_bit_cast(float, u);
}
// async global->LDS, 16B per lane. LDS dest is wave-uniform base + lane*16.
__device__ __forceinline__ void gload_lds16(const u16* g, u16* l) {
    __builtin_amdgcn_global_load_lds((const __attribute__((address_space(1))) void*)g,
                                     (__attribute__((address_space(3))) void*)l,
                                     16, 0, 0);
}

// ---------------- prep: cast X fp32->bf16  +  transpose-cast W -> Wt[N][K] bf16 ----------------
__global__ __launch_bounds__(256) void prep_kernel(const float* __restrict__ X,
                                                   const float* __restrict__ Wq,
                                                   const float* __restrict__ Wk,
                                                   const float* __restrict__ Wv,
                                                   u16* __restrict__ Xb,
                                                   u16* __restrict__ Wt) {
    __shared__ u16 tile[64 * 72];
    typedef float f4 __attribute__((ext_vector_type(4)));
    const int bid = blockIdx.x;
    if (bid < 8192) {                       // cast X: 8192 blocks * 256 thr * 4 elems
        const int idx = bid * 256 + threadIdx.x;
        f4 f = ((const f4*)X)[idx];
        u16x4 o;
        o[0] = f2bf(f[0]); o[1] = f2bf(f[1]); o[2] = f2bf(f[2]); o[3] = f2bf(f[3]);
        ((u16x4*)Xb)[idx] = o;
        return;
    }
    const int id = bid - 8192;              // 768 blocks: W transpose-cast
    const int z = id >> 8, rem = id & 255;
    const float* W = (z == 0) ? Wq : (z == 1) ? Wk : Wv;
    u16* out = Wt + ((size_t)z << 20);
    const int nt = (rem & 15) * 64, kt = (rem >> 4) * 64;
    const int t = threadIdx.x, r = t >> 2, cq = (t & 3) * 16;
    const float* src = W + (size_t)(kt + r) * 1024 + nt + cq;
#pragma unroll
    for (int q = 0; q < 4; q++) {
        f4 f = ((const f4*)src)[q];
        tile[r * 72 + cq + q * 4 + 0] = f2bf(f[0]);
        tile[r * 72 + cq + q * 4 + 1] = f2bf(f[1]);
        tile[r * 72 + cq + q * 4 + 2] = f2bf(f[2]);
        tile[r * 72 + cq + q * 4 + 3] = f2bf(f[3]);
    }
    __syncthreads();
    u16x8 o0, o1;
#pragma unroll
    for (int e = 0; e < 8; e++) { o0[e] = tile[(cq + e) * 72 + r]; o1[e] = tile[(cq + 8 + e) * 72 + r]; }
    u16* dst = out + (size_t)(nt + r) * 1024 + kt + cq;
    *(u16x8*)dst = o0;
    *(u16x8*)(dst + 8) = o1;
}

// ------------- shared GEMM core: C[M,N] = A[M,K] * Bt[N,K]^T -------------
// 128x128 tile, BK=32, 256 threads = 4 waves (2x2), 4x4 16x16x32 MFMA tiles/wave.
template <bool F32OUT>
__device__ __forceinline__ void gemm_bt_core(u16* __restrict__ smem,
                                             const u16* __restrict__ A,
                                             const u16* __restrict__ Bt,
                                             void* __restrict__ outp,
                                             const int ldk, const int ldo,
                                             const int kmax, const int m0, const int n0) {
    u16* As = smem;            // [128][32]
    u16* Bs = smem + 4096;     // [128][32]
    const int tid = (int)threadIdx.x;
    const int wave = tid >> 6, lane = tid & 63;
    const int wm = wave >> 1, wn = wave & 1;

    f32x4 acc[4][4] = {};

    const int sr = lane >> 2;            // row within 16-row issue group
    const int sc = (lane & 3) * 8;       // col chunk (8 bf16 = 16B)
    const u16* gA = A  + (size_t)(m0 + wave * 32 + sr) * ldk + sc;
    const u16* gB = Bt + (size_t)(n0 + wave * 32 + sr) * ldk + sc;
    u16* lA = As + wave * 1024;          // wave-uniform LDS base
    u16* lB = Bs + wave * 1024;
    const size_t rstep = (size_t)ldk * 16;

    const u16* pa = As + (wm * 64 + (lane & 15)) * 32 + (lane >> 4) * 8;
    const u16* pb = Bs + (wn * 64 + (lane & 15)) * 32 + (lane >> 4) * 8;

    for (int k0 = 0; k0 < kmax; k0 += 32) {
        gload_lds16(gA + k0,         lA);
        gload_lds16(gA + k0 + rstep, lA + 512);
        gload_lds16(gB + k0,         lB);
        gload_lds16(gB + k0 + rstep, lB + 512);
        __syncthreads();
        bf16x8 a[4], b[4];
#pragma unroll
        for (int i = 0; i < 4; i++) a[i] = *(const bf16x8*)(pa + i * 512);
#pragma unroll
        for (int j = 0; j < 4; j++) b[j] = *(const bf16x8*)(pb + j * 512);
#pragma unroll
        for (int i = 0; i < 4; i++)
#pragma unroll
            for (int j = 0; j < 4; j++)
                acc[i][j] = __builtin_amdgcn_mfma_f32_16x16x32_bf16(a[i], b[j], acc[i][j], 0, 0, 0);
        __syncthreads();
    }

    // epilogue: C/D layout col=lane&15, row=(lane>>4)*4+reg  [m89/m91-verified]
    const int row0 = m0 + wm * 64 + ((lane >> 4) << 2);
    const int col0 = n0 + wn * 64 + (lane & 15);
    if constexpr (F32OUT) {
        float* o = (float*)outp;
#pragma unroll
        for (int i = 0; i < 4; i++)
#pragma unroll
            for (int r = 0; r < 4; r++) {
                float* po = o + (size_t)(row0 + i * 16 + r) * ldo + col0;
#pragma unroll
                for (int j = 0; j < 4; j++) po[j * 16] = acc[i][j][r];
            }
    } else {
        u16* o = (u16*)outp;
#pragma unroll
        for (int i = 0; i < 4; i++)
#pragma unroll
            for (int r = 0; r < 4; r++) {
                u16* po = o + (size_t)(row0 + i * 16 + r) * ldo + col0;
#pragma unroll
                for (int j = 0; j < 4; j++) po[j * 16] = f2bf(acc[i][j][r]);
            }
    }
}

// QKV (one z per dispatch this round, for profile visibility):
// X[8192,1024] * Wt[z][1024,1024]^T -> QKV[z][8192,1024] bf16
__global__ __launch_bounds__(256) void qkv_gemm_kernel(const u16* __restrict__ Xb,
                                                       const u16* __restrict__ Wt,
                                                       u16* __restrict__ QKV, int z) {
    __shared__ u16 smem[8192];
    gemm_bt_core<false>(smem, Xb, Wt + ((size_t)z << 20), QKV + ((size_t)z << 23),
                        1024, 1024, 1024, blockIdx.y * 128, blockIdx.x * 128);
}

// fused: S = Q*K^T (544 causal tiles, compact triangular grid)  +  V transpose (2048 blocks)
__global__ __launch_bounds__(256) void s_tr_kernel(const u16* __restrict__ QKV,
                                                   u16* __restrict__ S,
                                                   u16* __restrict__ Vt) {
    __shared__ u16 smem[8192];
    const int bid = blockIdx.x;
    if (bid < 544) {
        const int b = bid / 136, t = bid - b * 136;
        int it = (int)((sqrtf(8.f * (float)t + 1.f) - 1.f) * 0.5f);
        while ((it + 1) * (it + 2) / 2 <= t) it++;
        while (it * (it + 1) / 2 > t) it--;
        const int jt = t - it * (it + 1) / 2;
        const u16* Q  = QKV + ((size_t)b << 21);
        const u16* Kp = QKV + ((size_t)1 << 23) + ((size_t)b << 21);
        gemm_bt_core<false>(smem, Q, Kp, S + ((size_t)b << 22), 1024, 2048, 1024,
                            it * 128, jt * 128);
        return;
    }
    // V[b][s][e] -> Vt[b][e][s], 64x64 tiles
    const int id = bid - 544;
    const int z = id >> 9, rem = id & 511;
    const u16* src = QKV + ((size_t)2 << 23) + ((size_t)z << 21);
    u16* dst = Vt + ((size_t)z << 21);
    const int st = (rem & 31) * 64, et = (rem >> 5) * 64;
    u16 (*tile)[72] = (u16(*)[72])smem;
    const int t = threadIdx.x, r = t >> 2, cq = (t & 3) * 16;
    const u16* p = src + (size_t)(st + r) * 1024 + et + cq;
    u16x8 u0 = *(const u16x8*)p;
    u16x8 u1 = *(const u16x8*)(p + 8);
#pragma unroll
    for (int e = 0; e < 8; e++) { tile[r][cq + e] = u0[e]; tile[r][cq + 8 + e] = u1[e]; }
    __syncthreads();
    u16x8 o0, o1;
#pragma unroll
    for (int e = 0; e < 8; e++) { o0[e] = tile[cq + e][r]; o1[e] = tile[cq + 8 + e][r]; }
    u16* q = dst + (size_t)(et + r) * 2048 + st + cq;
    *(u16x8*)q = o0;
    *(u16x8*)(q + 8) = o1;
}

// O = P * Vt^T per batch, k-loop truncated at causal boundary; longest-K blocks first
__global__ __launch_bounds__(256) void pv_gemm_kernel(const u16* __restrict__ P,
                                                      const u16* __restrict__ Vt,
                                                      float* __restrict__ O) {
    __shared__ u16 smem[8192];
    const int it = 15 - blockIdx.y, b = blockIdx.z;
    gemm_bt_core<true>(smem, P + ((size_t)b << 22), Vt + ((size_t)b << 21), O + ((size_t)b << 21),
                       2048, 1024, (it + 1) * 128, it * 128, blockIdx.x * 128);
}

// --------- in-place causal softmax (scale 1/32), truncated to kend=((i>>7)+1)*128 ---------
__global__ __launch_bounds__(256) void softmax_kernel(u16* __restrict__ S) {
    const int wave = threadIdx.x >> 6, lane = threadIdx.x & 63;
    const int g = blockIdx.x * 4 + wave;       // 0..8191
    const int b = g >> 11, i = g & 2047;
    u16* row = S + ((size_t)b << 22) + ((size_t)i << 11);
    const int n = i + 1;                        // valid keys
    const int kend = ((i >> 7) + 1) << 7;       // pv reads cols [0, kend)
    const int nt_ = (kend + 511) >> 9;          // active 512-col chunks (1..4), wave-uniform
    const float NEG = -1e30f;
    float v[32];
    float m = NEG;
#pragma unroll
    for (int t = 0; t < 4; t++) {
        if (t < nt_) {
            u16x8 u = *(const u16x8*)(row + t * 512 + lane * 8);
#pragma unroll
            for (int e = 0; e < 8; e++) {
                const int col = t * 512 + lane * 8 + e;
                float f = (col < n) ? bf2f(u[e]) : NEG;
                v[t * 8 + e] = f;
                m = fmaxf(m, f);
            }
        }
    }
#pragma unroll
    for (int off = 32; off > 0; off >>= 1) m = fmaxf(m, __shfl_xor(m, off, 64));
    const float sc = 0.03125f * 1.44269504088896f;   // (1/sqrt(1024)) * log2(e)
    float s = 0.f;
#pragma unroll
    for (int t = 0; t < 4; t++) {
        if (t < nt_) {
#pragma unroll
            for (int e = 0; e < 8; e++) {
                const float x = v[t * 8 + e];
                const float e2 = (x == NEG) ? 0.f : exp2f((x - m) * sc);
                v[t * 8 + e] = e2;
                s += e2;
            }
        }
    }
#pragma unroll
    for (int off = 32; off > 0; off >>= 1) s += __shfl_xor(s, off, 64);
    const float inv = 1.f / s;
#pragma unroll
    for (int t = 0; t < 4; t++) {
        if (t < nt_) {
            u16x8 o;
#pragma unroll
            for (int e = 0; e < 8; e++) o[e] = f2bf(v[t * 8 + e] * inv);
            *(u16x8*)(row + t * 512 + lane * 8) = o;
        }
    }
}

extern "C" void kernel_launch(void* const* d_in, const int* in_sizes, int n_in,
                              void* d_out, int out_size, void* d_ws, size_t ws_size,
                              hipStream_t stream) {
    const float* X  = (const float*)d_in[0];
    const float* Wq = (const float*)d_in[1];
    const float* Wk = (const float*)d_in[2];
    const float* Wv = (const float*)d_in[3];
    float* out = (float*)d_out;

    // ws layout (u16 elems): Xb 8M | Wt 3M | QKV 24M | S 16M  -> ~107 MB
    u16* ws  = (u16*)d_ws;
    u16* Xb  = ws;                                   // 1<<23 elems (reused as Vt)
    u16* Wt  = Xb + ((size_t)1 << 23);               // 3 * (1<<20)
    u16* QKV = Wt + 3 * ((size_t)1 << 20);           // 3 * (1<<23)
    u16* S   = QKV + 3 * ((size_t)1 << 23);          // 1<<24
    u16* Vt  = Xb;                                   // Xb dead after QKV GEMM

    prep_kernel<<<8960, 256, 0, stream>>>(X, Wq, Wk, Wv, Xb, Wt);
    qkv_gemm_kernel<<<dim3(8, 64), 256, 0, stream>>>(Xb, Wt, QKV, 0);
    qkv_gemm_kernel<<<dim3(8, 64), 256, 0, stream>>>(Xb, Wt, QKV, 1);
    qkv_gemm_kernel<<<dim3(8, 64), 256, 0, stream>>>(Xb, Wt, QKV, 2);
    s_tr_kernel<<<2592, 256, 0, stream>>>(QKV, S, Vt);
    softmax_kernel<<<2048, 256, 0, stream>>>(S);
    pv_gemm_kernel<<<dim3(8, 16, 4), 256, 0, stream>>>(S, Vt, out);
}

// Round 3
// 277.537 us; speedup vs baseline: 1.0328x; 1.0181x over previous
//
#include <hip/hip_runtime.h>
#include <cstdint>
#include <cmath>

typedef unsigned short u16;
typedef u16   u16x4  __attribute__((ext_vector_type(4)));
typedef u16   u16x8  __attribute__((ext_vector_type(8)));
typedef __bf16 bf16x8 __attribute__((ext_vector_type(8)));
typedef float f32x4  __attribute__((ext_vector_type(4)));

__device__ __forceinline__ u16 f2bf(float f) {
    uint32_t u = __builtin_bit_cast(uint32_t, f);
    u += 0x7fffu + ((u >> 16) & 1u);   // round-to-nearest-even
    return (u16)(u >> 16);
}
__device__ __forceinline__ float bf2f(u16 v) {
    uint32_t u = ((uint32_t)v) << 16;
    return __builtin_bit_cast(float, u);
}
// async global->LDS, 16B per lane. LDS dest is wave-uniform base + lane*16.
__device__ __forceinline__ void gload_lds16(const u16* g, u16* l) {
    __builtin_amdgcn_global_load_lds((const __attribute__((address_space(1))) void*)g,
                                     (__attribute__((address_space(3))) void*)l,
                                     16, 0, 0);
}

// ---------------- prep: cast X fp32->bf16  +  transpose-cast W -> Wt[N][K] bf16 ----------------
__global__ __launch_bounds__(256) void prep_kernel(const float* __restrict__ X,
                                                   const float* __restrict__ Wq,
                                                   const float* __restrict__ Wk,
                                                   const float* __restrict__ Wv,
                                                   u16* __restrict__ Xb,
                                                   u16* __restrict__ Wt) {
    __shared__ u16 tile[64 * 72];
    typedef float f4 __attribute__((ext_vector_type(4)));
    const int bid = blockIdx.x;
    if (bid < 8192) {                       // cast X: 8192 blocks * 256 thr * 4 elems
        const int idx = bid * 256 + threadIdx.x;
        f4 f = ((const f4*)X)[idx];
        u16x4 o;
        o[0] = f2bf(f[0]); o[1] = f2bf(f[1]); o[2] = f2bf(f[2]); o[3] = f2bf(f[3]);
        ((u16x4*)Xb)[idx] = o;
        return;
    }
    const int id = bid - 8192;              // 768 blocks: W transpose-cast
    const int z = id >> 8, rem = id & 255;
    const float* W = (z == 0) ? Wq : (z == 1) ? Wk : Wv;
    u16* out = Wt + ((size_t)z << 20);
    const int nt = (rem & 15) * 64, kt = (rem >> 4) * 64;
    const int t = threadIdx.x, r = t >> 2, cq = (t & 3) * 16;
    const float* src = W + (size_t)(kt + r) * 1024 + nt + cq;
#pragma unroll
    for (int q = 0; q < 4; q++) {
        f4 f = ((const f4*)src)[q];
        tile[r * 72 + cq + q * 4 + 0] = f2bf(f[0]);
        tile[r * 72 + cq + q * 4 + 1] = f2bf(f[1]);
        tile[r * 72 + cq + q * 4 + 2] = f2bf(f[2]);
        tile[r * 72 + cq + q * 4 + 3] = f2bf(f[3]);
    }
    __syncthreads();
    u16x8 o0, o1;
#pragma unroll
    for (int e = 0; e < 8; e++) { o0[e] = tile[(cq + e) * 72 + r]; o1[e] = tile[(cq + 8 + e) * 72 + r]; }
    u16* dst = out + (size_t)(nt + r) * 1024 + kt + cq;
    *(u16x8*)dst = o0;
    *(u16x8*)(dst + 8) = o1;
}

// ------------- shared GEMM core: C[M,N] = A[M,K] * Bt[N,K]^T -------------
// 128x128 tile, BK=32, 256 threads = 4 waves (2x2), 4x4 16x16x32 MFMA tiles/wave.
template <bool F32OUT>
__device__ __forceinline__ void gemm_bt_core(u16* __restrict__ smem,
                                             const u16* __restrict__ A,
                                             const u16* __restrict__ Bt,
                                             void* __restrict__ outp,
                                             const int ldk, const int ldo,
                                             const int kmax, const int m0, const int n0) {
    u16* As = smem;            // [128][32]
    u16* Bs = smem + 4096;     // [128][32]
    const int tid = (int)threadIdx.x;
    const int wave = tid >> 6, lane = tid & 63;
    const int wm = wave >> 1, wn = wave & 1;

    f32x4 acc[4][4] = {};

    const int sr = lane >> 2;            // row within 16-row issue group
    const int sc = (lane & 3) * 8;       // col chunk (8 bf16 = 16B)
    const u16* gA = A  + (size_t)(m0 + wave * 32 + sr) * ldk + sc;
    const u16* gB = Bt + (size_t)(n0 + wave * 32 + sr) * ldk + sc;
    u16* lA = As + wave * 1024;          // wave-uniform LDS base
    u16* lB = Bs + wave * 1024;
    const size_t rstep = (size_t)ldk * 16;

    const u16* pa = As + (wm * 64 + (lane & 15)) * 32 + (lane >> 4) * 8;
    const u16* pb = Bs + (wn * 64 + (lane & 15)) * 32 + (lane >> 4) * 8;

    for (int k0 = 0; k0 < kmax; k0 += 32) {
        gload_lds16(gA + k0,         lA);
        gload_lds16(gA + k0 + rstep, lA + 512);
        gload_lds16(gB + k0,         lB);
        gload_lds16(gB + k0 + rstep, lB + 512);
        __syncthreads();
        bf16x8 a[4], b[4];
#pragma unroll
        for (int i = 0; i < 4; i++) a[i] = *(const bf16x8*)(pa + i * 512);
#pragma unroll
        for (int j = 0; j < 4; j++) b[j] = *(const bf16x8*)(pb + j * 512);
#pragma unroll
        for (int i = 0; i < 4; i++)
#pragma unroll
            for (int j = 0; j < 4; j++)
                acc[i][j] = __builtin_amdgcn_mfma_f32_16x16x32_bf16(a[i], b[j], acc[i][j], 0, 0, 0);
        __syncthreads();
    }

    // epilogue: C/D layout col=lane&15, row=(lane>>4)*4+reg  [m89/m91-verified]
    const int row0 = m0 + wm * 64 + ((lane >> 4) << 2);
    const int col0 = n0 + wn * 64 + (lane & 15);
    if constexpr (F32OUT) {
        float* o = (float*)outp;
#pragma unroll
        for (int i = 0; i < 4; i++)
#pragma unroll
            for (int r = 0; r < 4; r++) {
                float* po = o + (size_t)(row0 + i * 16 + r) * ldo + col0;
#pragma unroll
                for (int j = 0; j < 4; j++) po[j * 16] = acc[i][j][r];
            }
    } else {
        u16* o = (u16*)outp;
#pragma unroll
        for (int i = 0; i < 4; i++)
#pragma unroll
            for (int r = 0; r < 4; r++) {
                u16* po = o + (size_t)(row0 + i * 16 + r) * ldo + col0;
#pragma unroll
                for (int j = 0; j < 4; j++) po[j * 16] = f2bf(acc[i][j][r]);
            }
    }
}

// QKV (one z per dispatch for profile visibility; measured split cost ~0):
// X[8192,1024] * Wt[z][1024,1024]^T -> QKV[z][8192,1024] bf16
__global__ __launch_bounds__(256) void qkv_gemm_kernel(const u16* __restrict__ Xb,
                                                       const u16* __restrict__ Wt,
                                                       u16* __restrict__ QKV, int z) {
    __shared__ u16 smem[8192];
    gemm_bt_core<false>(smem, Xb, Wt + ((size_t)z << 20), QKV + ((size_t)z << 23),
                        1024, 1024, 1024, blockIdx.y * 128, blockIdx.x * 128);
}

// fused: S = Q*K^T (544 causal tiles, compact triangular grid)  +  V transpose (2048 blocks)
__global__ __launch_bounds__(256) void s_tr_kernel(const u16* __restrict__ QKV,
                                                   u16* __restrict__ S,
                                                   u16* __restrict__ Vt) {
    __shared__ u16 smem[8192];
    const int bid = blockIdx.x;
    if (bid < 544) {
        const int b = bid / 136, t = bid - b * 136;
        int it = (int)((sqrtf(8.f * (float)t + 1.f) - 1.f) * 0.5f);
        while ((it + 1) * (it + 2) / 2 <= t) it++;
        while (it * (it + 1) / 2 > t) it--;
        const int jt = t - it * (it + 1) / 2;
        const u16* Q  = QKV + ((size_t)b << 21);
        const u16* Kp = QKV + ((size_t)1 << 23) + ((size_t)b << 21);
        gemm_bt_core<false>(smem, Q, Kp, S + ((size_t)b << 22), 1024, 2048, 1024,
                            it * 128, jt * 128);
        return;
    }
    // V[b][s][e] -> Vt[b][e][s], 64x64 tiles
    const int id = bid - 544;
    const int z = id >> 9, rem = id & 511;
    const u16* src = QKV + ((size_t)2 << 23) + ((size_t)z << 21);
    u16* dst = Vt + ((size_t)z << 21);
    const int st = (rem & 31) * 64, et = (rem >> 5) * 64;
    u16 (*tile)[72] = (u16(*)[72])smem;
    const int t = threadIdx.x, r = t >> 2, cq = (t & 3) * 16;
    const u16* p = src + (size_t)(st + r) * 1024 + et + cq;
    u16x8 u0 = *(const u16x8*)p;
    u16x8 u1 = *(const u16x8*)(p + 8);
#pragma unroll
    for (int e = 0; e < 8; e++) { tile[r][cq + e] = u0[e]; tile[r][cq + 8 + e] = u1[e]; }
    __syncthreads();
    u16x8 o0, o1;
#pragma unroll
    for (int e = 0; e < 8; e++) { o0[e] = tile[cq + e][r]; o1[e] = tile[cq + 8 + e][r]; }
    u16* q = dst + (size_t)(et + r) * 2048 + st + cq;
    *(u16x8*)q = o0;
    *(u16x8*)(q + 8) = o1;
}

// O = P * Vt^T per batch, k-loop truncated at causal boundary.
// CU-load-balanced schedule: tiles sorted by descending K (it), antisymmetric
// pairing so CU c (getting blocks c and c+256 under linear/XCD-round-robin
// dispatch) always sums to 17 K128-units. Fixes R2's 2x-K2048-on-one-CU path.
__global__ __launch_bounds__(256) void pv_gemm_kernel(const u16* __restrict__ P,
                                                      const u16* __restrict__ Vt,
                                                      float* __restrict__ O) {
    __shared__ u16 smem[8192];
    const int j = blockIdx.x;                    // 0..511
    const int i = (j < 256) ? j : 767 - j;       // index into K-descending sorted tile list
    const int it = 15 - (i >> 5);                // 32 tiles per it value
    const int rem = i & 31;
    const int b = rem >> 3;
    const int n0 = (rem & 7) * 128;
    gemm_bt_core<true>(smem, P + ((size_t)b << 22), Vt + ((size_t)b << 21), O + ((size_t)b << 21),
                       2048, 1024, (it + 1) * 128, it * 128, n0);
}

// --------- in-place causal softmax (scale 1/32), truncated to kend=((i>>7)+1)*128 ---------
__global__ __launch_bounds__(256) void softmax_kernel(u16* __restrict__ S) {
    const int wave = threadIdx.x >> 6, lane = threadIdx.x & 63;
    const int g = blockIdx.x * 4 + wave;       // 0..8191
    const int b = g >> 11, i = g & 2047;
    u16* row = S + ((size_t)b << 22) + ((size_t)i << 11);
    const int n = i + 1;                        // valid keys
    const int kend = ((i >> 7) + 1) << 7;       // pv reads cols [0, kend)
    const int nt_ = (kend + 511) >> 9;          // active 512-col chunks (1..4), wave-uniform
    const float NEG = -1e30f;
    float v[32];
    float m = NEG;
#pragma unroll
    for (int t = 0; t < 4; t++) {
        if (t < nt_) {
            u16x8 u = *(const u16x8*)(row + t * 512 + lane * 8);
#pragma unroll
            for (int e = 0; e < 8; e++) {
                const int col = t * 512 + lane * 8 + e;
                float f = (col < n) ? bf2f(u[e]) : NEG;
                v[t * 8 + e] = f;
                m = fmaxf(m, f);
            }
        }
    }
#pragma unroll
    for (int off = 32; off > 0; off >>= 1) m = fmaxf(m, __shfl_xor(m, off, 64));
    const float sc = 0.03125f * 1.44269504088896f;   // (1/sqrt(1024)) * log2(e)
    float s = 0.f;
#pragma unroll
    for (int t = 0; t < 4; t++) {
        if (t < nt_) {
#pragma unroll
            for (int e = 0; e < 8; e++) {
                const float x = v[t * 8 + e];
                const float e2 = (x == NEG) ? 0.f : exp2f((x - m) * sc);
                v[t * 8 + e] = e2;
                s += e2;
            }
        }
    }
#pragma unroll
    for (int off = 32; off > 0; off >>= 1) s += __shfl_xor(s, off, 64);
    const float inv = 1.f / s;
#pragma unroll
    for (int t = 0; t < 4; t++) {
        if (t < nt_) {
            u16x8 o;
#pragma unroll
            for (int e = 0; e < 8; e++) o[e] = f2bf(v[t * 8 + e] * inv);
            *(u16x8*)(row + t * 512 + lane * 8) = o;
        }
    }
}

extern "C" void kernel_launch(void* const* d_in, const int* in_sizes, int n_in,
                              void* d_out, int out_size, void* d_ws, size_t ws_size,
                              hipStream_t stream) {
    const float* X  = (const float*)d_in[0];
    const float* Wq = (const float*)d_in[1];
    const float* Wk = (const float*)d_in[2];
    const float* Wv = (const float*)d_in[3];
    float* out = (float*)d_out;

    // ws layout (u16 elems): Xb 8M | Wt 3M | QKV 24M | S 16M  -> ~107 MB
    u16* ws  = (u16*)d_ws;
    u16* Xb  = ws;                                   // 1<<23 elems (reused as Vt)
    u16* Wt  = Xb + ((size_t)1 << 23);               // 3 * (1<<20)
    u16* QKV = Wt + 3 * ((size_t)1 << 20);           // 3 * (1<<23)
    u16* S   = QKV + 3 * ((size_t)1 << 23);          // 1<<24
    u16* Vt  = Xb;                                   // Xb dead after QKV GEMM

    prep_kernel<<<8960, 256, 0, stream>>>(X, Wq, Wk, Wv, Xb, Wt);
    qkv_gemm_kernel<<<dim3(8, 64), 256, 0, stream>>>(Xb, Wt, QKV, 0);
    qkv_gemm_kernel<<<dim3(8, 64), 256, 0, stream>>>(Xb, Wt, QKV, 1);
    qkv_gemm_kernel<<<dim3(8, 64), 256, 0, stream>>>(Xb, Wt, QKV, 2);
    s_tr_kernel<<<2592, 256, 0, stream>>>(QKV, S, Vt);
    softmax_kernel<<<2048, 256, 0, stream>>>(S);
    pv_gemm_kernel<<<512, 256, 0, stream>>>(S, Vt, out);
}